// Round 13
// baseline (315.511 us; speedup 1.0000x reference)
//
#include <hip/hip_runtime.h>

#define SEQ   4096
#define HH    4
#define SCALE 0.125f

typedef __bf16 bf16x8 __attribute__((ext_vector_type(8)));
typedef __bf16 bf16x4 __attribute__((ext_vector_type(4)));
typedef short  s16x4  __attribute__((ext_vector_type(4)));
typedef float  f32x4  __attribute__((ext_vector_type(4)));

// ---- ws layout (float offsets) ----
// Facts: inputs fp32, output fp32 (R6), ws >= 70.5 MB (R2==R3).
// Q,K frag-packed [bh][tile16][frag2][lane64][e8] (A/B of 16x16x32).
// V packed as V^T A-frags for 16x16x16: [bh][jc16][nd4][lane64][e4].
constexpr size_t OFF_W16  = 0;         // 4x65536 bf16 weights row-major
constexpr size_t OFF_A    = 131072;    // [bh*S+j] a_j = -16 - ln(Z_j)
constexpr size_t OFF_PZ   = 163840;    // [4][32768]
constexpr size_t OFF_AO   = 294912;    // [8192][256] fp32 attn out (atomic)
constexpr size_t OFF_X16  = 9732096;   // 6291456 bf16 (x cast)
constexpr size_t OFF_Q16  = 12877824;  // packed Q,K,V bf16 regions
constexpr size_t K16OFF   = 2097152;
constexpr size_t V16OFF   = 4194304;

__device__ __forceinline__ f32x4 mf(bf16x8 a, bf16x8 b, f32x4 c) {
    return __builtin_amdgcn_mfma_f32_16x16x32_bf16(a, b, c, 0, 0, 0);
}

// K=16 bf16 MFMA (PV step): A,B = 4 bf16 (2 VGPRs each)
__device__ __forceinline__ f32x4 mf16(bf16x4 a, bf16x4 b, f32x4 c) {
#if __has_builtin(__builtin_amdgcn_mfma_f32_16x16x16bf16_1k)
    s16x4 as = __builtin_bit_cast(s16x4, a);
    s16x4 bs = __builtin_bit_cast(s16x4, b);
    return __builtin_amdgcn_mfma_f32_16x16x16bf16_1k(as, bs, c, 0, 0, 0);
#else
    f32x4 d = c;
    asm volatile("v_mfma_f32_16x16x16_bf16 %0, %1, %2, %0"
                 : "+v"(d) : "v"(a), "v"(b));
    return d;
#endif
}

// async global->LDS, 16B/lane
__device__ __forceinline__ void gload16(const __bf16* g, __bf16* l) {
    __builtin_amdgcn_global_load_lds(
        (const __attribute__((address_space(1))) unsigned int*)g,
        (__attribute__((address_space(3))) unsigned int*)l, 16, 0, 0);
}

// ---- prep: cast x, cast weights, zero AO ----
__global__ void k_prep(const float* __restrict__ x,
                       const float* __restrict__ wq, const float* __restrict__ wk,
                       const float* __restrict__ wv, const float* __restrict__ wo,
                       float* __restrict__ ws) {
    int bx = blockIdx.x, t = threadIdx.x;
    if (bx < 6144) {
        size_t i4 = ((size_t)bx * 256 + t) * 4;
        float4 v = *(const float4*)(x + i4);
        bf16x4 o = {(__bf16)v.x, (__bf16)v.y, (__bf16)v.z, (__bf16)v.w};
        *(bf16x4*)((__bf16*)(ws + OFF_X16) + i4) = o;
    } else if (bx < 6400) {
        int q = bx - 6144;
        int y = q >> 6;
        const float* src = (y == 0) ? wq : (y == 1) ? wk : (y == 2) ? wv : wo;
        size_t i4 = ((size_t)(q & 63) * 256 + t) * 4;
        float4 v = *(const float4*)(src + i4);
        bf16x4 o = {(__bf16)v.x, (__bf16)v.y, (__bf16)v.z, (__bf16)v.w};
        *(bf16x4*)((__bf16*)(ws + OFF_W16) + (size_t)y * 65536 + i4) = o;
    } else {
        size_t i4 = ((size_t)(bx - 6400) * 256 + t) * 4;
        *(float4*)(ws + OFF_AO + i4) = make_float4(0.f, 0.f, 0.f, 0.f);
    }
}

// ---- QKV projection via MFMA; epilogue writes frag-packed layouts ----
__global__ __launch_bounds__(256) void k_qkv_mfma(const float* __restrict__ bq,
                                                  const float* __restrict__ bk,
                                                  const float* __restrict__ bv,
                                                  float* __restrict__ ws) {
    int t = threadIdx.x, lane = t & 63, w = t >> 6;
    int yw = blockIdx.y;
    int row0 = blockIdx.x * 64 + w * 16;
    int mrow = lane & 15, quad = lane >> 4;
    const __bf16* X16 = (const __bf16*)(ws + OFF_X16);
    const __bf16* W16 = (const __bf16*)(ws + OFF_W16) + (size_t)yw * 65536;
    const float* bias = (yw == 0) ? bq : (yw == 1) ? bk : bv;
    __bf16* Qb = (__bf16*)(ws + OFF_Q16);
    f32x4 acc[16];
#pragma unroll
    for (int n = 0; n < 16; n++) acc[n] = {0.f, 0.f, 0.f, 0.f};
    const __bf16* ap = X16 + (size_t)(row0 + mrow) * 768 + yw * 256 + quad * 8;
    const __bf16* bp = W16 + (size_t)mrow * 256 + quad * 8;
    for (int kc = 0; kc < 256; kc += 32) {
        bf16x8 a = *(const bf16x8*)(ap + kc);
#pragma unroll
        for (int nt = 0; nt < 16; nt++) {
            bf16x8 b = *(const bf16x8*)(bp + (size_t)nt * 16 * 256 + kc);
            acc[nt] = mf(a, b, acc[nt]);
        }
    }
#pragma unroll
    for (int nt = 0; nt < 16; nt++) {
        int n = nt * 16 + mrow;
        float bb = bias[n];
        int h = n >> 6, d = n & 63;
#pragma unroll
        for (int r = 0; r < 4; r++) {
            int sg = row0 + quad * 4 + r;
            int b_ = sg >> 12, s = sg & 4095;
            int bh = b_ * HH + h;
            float val = acc[nt][r] + bb;
            if (yw <= 1) {
                int tile = s >> 4, m = s & 15, frag = d >> 5, q2 = (d >> 3) & 3, e = d & 7;
                size_t idx = (((size_t)bh * 256 + tile) * 2 + frag) * 512 +
                             (size_t)(q2 * 16 + m) * 8 + e;
                ((yw == 0) ? Qb : Qb + K16OFF)[idx] = (__bf16)val;
            } else {
                // V^T A-frag layout: [bh][jc16][nd4][(q*16+dl)*4+e], j=s, d
                int jc = s >> 4, q = (s >> 2) & 3, e = s & 3;
                int nd = d >> 4, dl = d & 15;
                size_t idx = (((size_t)bh * 256 + jc) * 4 + nd) * 256 +
                             (size_t)(q * 16 + dl) * 4 + e;
                Qb[V16OFF + idx] = (__bf16)val;
            }
        }
    }
}

// ---- pass 1: Z_j = sum_i exp(s_ij - 16); 32 j/wave, Q staged in LDS ----
__global__ __launch_bounds__(256) void k_colstats(float* __restrict__ ws) {
    __shared__ __bf16 qbuf[2][4096];
    int t = threadIdx.x, lane = t & 63, w = t >> 6;
    int jb = blockIdx.x, iy = blockIdx.y, bh = blockIdx.z;
    int jt0 = jb * 8 + w * 2;
    const __bf16* Qp = (const __bf16*)(ws + OFF_Q16);
    const __bf16* Kp = Qp + K16OFF;
    const __bf16* kb = Kp + (((size_t)bh * 256 + jt0) * 2) * 512 + lane * 8;
    bf16x8 bk00 = *(const bf16x8*)(kb);
    bf16x8 bk01 = *(const bf16x8*)(kb + 512);
    bf16x8 bk10 = *(const bf16x8*)(kb + 1024);
    bf16x8 bk11 = *(const bf16x8*)(kb + 1536);
    const __bf16* q0 = Qp + (((size_t)bh * 256 + iy * 64) * 2) * 512 +
                       w * 1024 + lane * 8;
    gload16(q0, qbuf[0] + w * 1024);
    gload16(q0 + 512, qbuf[0] + w * 1024 + 512);
    __syncthreads();
    float z0 = 0.f, z1 = 0.f;
    for (int ic = 0; ic < 16; ic++) {
        const __bf16* cur = qbuf[ic & 1];
        if (ic < 15) {
            const __bf16* qn = Qp + (((size_t)bh * 256 + iy * 64 + (ic + 1) * 4) * 2) * 512 +
                               w * 1024 + lane * 8;
            gload16(qn, qbuf[(ic + 1) & 1] + w * 1024);
            gload16(qn + 512, qbuf[(ic + 1) & 1] + w * 1024 + 512);
        }
#pragma unroll
        for (int it = 0; it < 4; it++) {
            bf16x8 a0 = *(const bf16x8*)(cur + it * 1024 + lane * 8);
            bf16x8 a1 = *(const bf16x8*)(cur + it * 1024 + 512 + lane * 8);
            f32x4 c0 = {0.f, 0.f, 0.f, 0.f};
            c0 = mf(a0, bk00, c0);
            c0 = mf(a1, bk01, c0);
            f32x4 c1 = {0.f, 0.f, 0.f, 0.f};
            c1 = mf(a0, bk10, c1);
            c1 = mf(a1, bk11, c1);
#pragma unroll
            for (int r = 0; r < 4; r++) {
                z0 += __expf(fmaf(c0[r], SCALE, -16.0f));
                z1 += __expf(fmaf(c1[r], SCALE, -16.0f));
            }
        }
        __syncthreads();
    }
    z0 += __shfl_xor(z0, 16, 64);
    z0 += __shfl_xor(z0, 32, 64);
    z1 += __shfl_xor(z1, 16, 64);
    z1 += __shfl_xor(z1, 32, 64);
    if (lane < 16) {
        size_t o = OFF_PZ + (size_t)iy * 32768 + (size_t)bh * SEQ + jt0 * 16 + lane;
        ws[o] = z0;
        ws[o + 16] = z1;
    }
}

// ---- pass 1b: a_j = -16 - ln(sum of partials) ----
__global__ void k_afin(float* __restrict__ ws) {
    int idx = blockIdx.x * 256 + threadIdx.x;
    const float* pz = ws + OFF_PZ;
    float Z = pz[idx] + pz[32768 + (size_t)idx] + pz[65536 + (size_t)idx] +
              pz[98304 + (size_t)idx];
    ws[OFF_A + idx] = -16.0f - __logf(Z);
}

// ---- pass 2: S^T trick — P stays in registers, no LDS round-trip ----
// grid (32 ib, 4 jy, 8 bh); wave owns 32 i; chunks of 32 j, double-buffered.
// S^T = mf(K,Q): col=i, row=j=quad*4+r; P packs directly as B of 16x16x16;
// O^T[d][i] += mf16(V^T_frag, P_frag).
__global__ __launch_bounds__(256) void k_attnpv(float* __restrict__ ws) {
    __shared__ __bf16 ldsK[2][2048], ldsV[2][2048];
    int t = threadIdx.x, lane = t & 63, w = t >> 6;
    int jy = blockIdx.y, bh = blockIdx.z;
    int it0 = blockIdx.x * 8 + w * 2;
    int mrow = lane & 15, quad = lane >> 4;
    const __bf16* Qp = (const __bf16*)(ws + OFF_Q16);
    const __bf16* Kp = Qp + K16OFF;
    const __bf16* Vp = Qp + V16OFF;
    const float* Ac = ws + OFF_A + (size_t)bh * SEQ;

    const __bf16* qb = Qp + (((size_t)bh * 256 + it0) * 2) * 512 + lane * 8;
    bf16x8 qf[2][2];
    qf[0][0] = *(const bf16x8*)(qb);
    qf[0][1] = *(const bf16x8*)(qb + 512);
    qf[1][0] = *(const bf16x8*)(qb + 1024);
    qf[1][1] = *(const bf16x8*)(qb + 1536);

    f32x4 oacc[2][4];
#pragma unroll
    for (int tt = 0; tt < 2; tt++)
#pragma unroll
        for (int nd = 0; nd < 4; nd++) oacc[tt][nd] = {0.f, 0.f, 0.f, 0.f};

    int jbase = jy * 1024;
    {
        const __bf16* kg = Kp + (((size_t)bh * 256 + (jbase >> 4)) * 2) * 512 +
                           w * 512 + lane * 8;
        gload16(kg, ldsK[0] + w * 512);
        const __bf16* vg = Vp + ((size_t)bh * 256 + (jbase >> 4)) * 1024 +
                           w * 512 + lane * 8;
        gload16(vg, ldsV[0] + w * 512);
    }
    __syncthreads();

    for (int jt = 0; jt < 32; jt++) {
        int j0 = jbase + jt * 32;
        const __bf16* curK = ldsK[jt & 1];
        const __bf16* curV = ldsV[jt & 1];
        if (jt < 31) {
            int jn = j0 + 32;
            const __bf16* kg = Kp + (((size_t)bh * 256 + (jn >> 4)) * 2) * 512 +
                               w * 512 + lane * 8;
            gload16(kg, ldsK[(jt + 1) & 1] + w * 512);
            const __bf16* vg = Vp + ((size_t)bh * 256 + (jn >> 4)) * 1024 +
                               w * 512 + lane * 8;
            gload16(vg, ldsV[(jt + 1) & 1] + w * 512);
        }
#pragma unroll
        for (int jj = 0; jj < 2; jj++) {
            bf16x8 k0 = *(const bf16x8*)(curK + (jj * 2) * 512 + lane * 8);
            bf16x8 k1 = *(const bf16x8*)(curK + (jj * 2 + 1) * 512 + lane * 8);
            bf16x4 vf[4];
#pragma unroll
            for (int nd = 0; nd < 4; nd++)
                vf[nd] = *(const bf16x4*)(curV + (jj * 4 + nd) * 256 + lane * 4);
            float4 af = *(const float4*)(Ac + j0 + jj * 16 + quad * 4);
#pragma unroll
            for (int tt = 0; tt < 2; tt++) {
                f32x4 c = {0.f, 0.f, 0.f, 0.f};
                c = mf(k0, qf[tt][0], c);   // A=K (m=j), B=Q (n=i) -> S^T
                c = mf(k1, qf[tt][1], c);
                bf16x4 pf;
                pf[0] = (__bf16)__expf(fmaf(c[0], SCALE, af.x));
                pf[1] = (__bf16)__expf(fmaf(c[1], SCALE, af.y));
                pf[2] = (__bf16)__expf(fmaf(c[2], SCALE, af.z));
                pf[3] = (__bf16)__expf(fmaf(c[3], SCALE, af.w));
#pragma unroll
                for (int nd = 0; nd < 4; nd++)
                    oacc[tt][nd] = mf16(vf[nd], pf, oacc[tt][nd]);
            }
        }
        __syncthreads();
    }

    int b = bh >> 2, h = bh & 3;
    float* AO = ws + OFF_AO;
#pragma unroll
    for (int tt = 0; tt < 2; tt++) {
        int i = (it0 + tt) * 16 + mrow;          // O^T: col = i = lane&15
#pragma unroll
        for (int nd = 0; nd < 4; nd++) {
#pragma unroll
            for (int r = 0; r < 4; r++) {
                int d = nd * 16 + quad * 4 + r;  // row = d
                atomicAdd(&AO[((size_t)(b * SEQ + i)) * 256 + h * 64 + d],
                          oacc[tt][nd][r]);
            }
        }
    }
}

// ---- output projection: fp32 AO -> bf16 frags inline, MFMA, fp32 out ----
__global__ __launch_bounds__(256) void k_outproj_mfma(const float* __restrict__ bo,
                                                      float* __restrict__ ws,
                                                      float* __restrict__ out) {
    int t = threadIdx.x, lane = t & 63, w = t >> 6;
    int row0 = blockIdx.x * 64 + w * 16;
    int mrow = lane & 15, quad = lane >> 4;
    const float* AO = ws + OFF_AO;
    const __bf16* W16 = (const __bf16*)(ws + OFF_W16) + (size_t)3 * 65536;
    f32x4 acc[16];
#pragma unroll
    for (int n = 0; n < 16; n++) acc[n] = {0.f, 0.f, 0.f, 0.f};
    const float* ap = AO + (size_t)(row0 + mrow) * 256 + quad * 8;
    const __bf16* bp = W16 + (size_t)mrow * 256 + quad * 8;
    for (int kc = 0; kc < 256; kc += 32) {
        float4 u = *(const float4*)(ap + kc);
        float4 v = *(const float4*)(ap + kc + 4);
        bf16x8 a = {(__bf16)u.x, (__bf16)u.y, (__bf16)u.z, (__bf16)u.w,
                    (__bf16)v.x, (__bf16)v.y, (__bf16)v.z, (__bf16)v.w};
#pragma unroll
        for (int nt = 0; nt < 16; nt++) {
            bf16x8 b = *(const bf16x8*)(bp + (size_t)nt * 16 * 256 + kc);
            acc[nt] = mf(a, b, acc[nt]);
        }
    }
#pragma unroll
    for (int nt = 0; nt < 16; nt++) {
        int n = nt * 16 + mrow;
        float bb = bo[n];
#pragma unroll
        for (int r = 0; r < 4; r++) {
            int sg = row0 + quad * 4 + r;
            out[(size_t)sg * 256 + n] = acc[nt][r] + bb;
        }
    }
}

extern "C" void kernel_launch(void* const* d_in, const int* in_sizes, int n_in,
                              void* d_out, int out_size, void* d_ws, size_t ws_size,
                              hipStream_t stream) {
    const float* x  = (const float*)d_in[0];
    const float* wq = (const float*)d_in[1];
    const float* bq = (const float*)d_in[2];
    const float* wk = (const float*)d_in[3];
    const float* bk = (const float*)d_in[4];
    const float* wv = (const float*)d_in[5];
    const float* bv = (const float*)d_in[6];
    const float* wo = (const float*)d_in[7];
    const float* bo = (const float*)d_in[8];
    float* ws = (float*)d_ws;
    float* out = (float*)d_out;

    k_prep<<<8448, 256, 0, stream>>>(x, wq, wk, wv, wo, ws);
    k_qkv_mfma<<<dim3(128, 3), 256, 0, stream>>>(bq, bk, bv, ws);
    k_colstats<<<dim3(32, 4, 8), 256, 0, stream>>>(ws);
    k_afin<<<128, 256, 0, stream>>>(ws);
    k_attnpv<<<dim3(32, 4, 8), 256, 0, stream>>>(ws);
    k_outproj_mfma<<<128, 256, 0, stream>>>(bo, ws, out);
}

// Round 14
// 257.847 us; speedup vs baseline: 1.2236x; 1.2236x over previous
//
#include <hip/hip_runtime.h>

#define SEQ   4096
#define HH    4
#define SCALE 0.125f

typedef __bf16 bf16x8 __attribute__((ext_vector_type(8)));
typedef __bf16 bf16x4 __attribute__((ext_vector_type(4)));
typedef float  f32x4  __attribute__((ext_vector_type(4)));

// ---- ws layout (float offsets) ----
// Facts: inputs fp32, output fp32 (R6), ws >= 70.5 MB (R2==R3).
// Q,K frag-packed [bh][tile16][frag2][lane64][e8]; V: [bh][jc32][nd4][512].
constexpr size_t OFF_W16  = 0;         // 4x65536 bf16 weights row-major
constexpr size_t OFF_A    = 131072;    // [bh*S+j] a_j = -16 - ln(Z_j)
constexpr size_t OFF_PZ   = 163840;    // [8][32768] partial sums
constexpr size_t OFF_AO   = 425984;    // [8192][256] fp32 attn out (atomic)
constexpr size_t OFF_X16  = 9732096;   // 6291456 bf16 (x cast)
constexpr size_t OFF_Q16  = 12877824;  // packed Q,K,V bf16 regions
constexpr size_t K16OFF   = 2097152;
constexpr size_t V16OFF   = 4194304;

__device__ __forceinline__ f32x4 mf(bf16x8 a, bf16x8 b, f32x4 c) {
    return __builtin_amdgcn_mfma_f32_16x16x32_bf16(a, b, c, 0, 0, 0);
}

// async global->LDS, 16B/lane
__device__ __forceinline__ void gload16(const __bf16* g, __bf16* l) {
    __builtin_amdgcn_global_load_lds(
        (const __attribute__((address_space(1))) unsigned int*)g,
        (__attribute__((address_space(3))) unsigned int*)l, 16, 0, 0);
}

// ---- prep: cast x, cast weights, zero AO ----
__global__ void k_prep(const float* __restrict__ x,
                       const float* __restrict__ wq, const float* __restrict__ wk,
                       const float* __restrict__ wv, const float* __restrict__ wo,
                       float* __restrict__ ws) {
    int bx = blockIdx.x, t = threadIdx.x;
    if (bx < 6144) {
        size_t i4 = ((size_t)bx * 256 + t) * 4;
        float4 v = *(const float4*)(x + i4);
        bf16x4 o = {(__bf16)v.x, (__bf16)v.y, (__bf16)v.z, (__bf16)v.w};
        *(bf16x4*)((__bf16*)(ws + OFF_X16) + i4) = o;
    } else if (bx < 6400) {
        int q = bx - 6144;
        int y = q >> 6;
        const float* src = (y == 0) ? wq : (y == 1) ? wk : (y == 2) ? wv : wo;
        size_t i4 = ((size_t)(q & 63) * 256 + t) * 4;
        float4 v = *(const float4*)(src + i4);
        bf16x4 o = {(__bf16)v.x, (__bf16)v.y, (__bf16)v.z, (__bf16)v.w};
        *(bf16x4*)((__bf16*)(ws + OFF_W16) + (size_t)y * 65536 + i4) = o;
    } else {
        size_t i4 = ((size_t)(bx - 6400) * 256 + t) * 4;
        *(float4*)(ws + OFF_AO + i4) = make_float4(0.f, 0.f, 0.f, 0.f);
    }
}

// ---- QKV projection via MFMA; epilogue writes frag-packed layouts ----
__global__ __launch_bounds__(256) void k_qkv_mfma(const float* __restrict__ bq,
                                                  const float* __restrict__ bk,
                                                  const float* __restrict__ bv,
                                                  float* __restrict__ ws) {
    int t = threadIdx.x, lane = t & 63, w = t >> 6;
    int yw = blockIdx.y;
    int row0 = blockIdx.x * 64 + w * 16;
    int mrow = lane & 15, quad = lane >> 4;
    const __bf16* X16 = (const __bf16*)(ws + OFF_X16);
    const __bf16* W16 = (const __bf16*)(ws + OFF_W16) + (size_t)yw * 65536;
    const float* bias = (yw == 0) ? bq : (yw == 1) ? bk : bv;
    __bf16* Qb = (__bf16*)(ws + OFF_Q16);
    f32x4 acc[16];
#pragma unroll
    for (int n = 0; n < 16; n++) acc[n] = {0.f, 0.f, 0.f, 0.f};
    const __bf16* ap = X16 + (size_t)(row0 + mrow) * 768 + yw * 256 + quad * 8;
    const __bf16* bp = W16 + (size_t)mrow * 256 + quad * 8;
    for (int kc = 0; kc < 256; kc += 32) {
        bf16x8 a = *(const bf16x8*)(ap + kc);
#pragma unroll
        for (int nt = 0; nt < 16; nt++) {
            bf16x8 b = *(const bf16x8*)(bp + (size_t)nt * 16 * 256 + kc);
            acc[nt] = mf(a, b, acc[nt]);
        }
    }
#pragma unroll
    for (int nt = 0; nt < 16; nt++) {
        int n = nt * 16 + mrow;
        float bb = bias[n];
        int h = n >> 6, d = n & 63;
#pragma unroll
        for (int r = 0; r < 4; r++) {
            int sg = row0 + quad * 4 + r;
            int b_ = sg >> 12, s = sg & 4095;
            int bh = b_ * HH + h;
            float val = acc[nt][r] + bb;
            if (yw <= 1) {
                int tile = s >> 4, m = s & 15, frag = d >> 5, q2 = (d >> 3) & 3, e = d & 7;
                size_t idx = (((size_t)bh * 256 + tile) * 2 + frag) * 512 +
                             (size_t)(q2 * 16 + m) * 8 + e;
                ((yw == 0) ? Qb : Qb + K16OFF)[idx] = (__bf16)val;
            } else {
                int jc = s >> 5, qk = (s >> 3) & 3, e = s & 7;
                int nd = d >> 4, nl = d & 15;
                size_t idx = (((size_t)bh * 128 + jc) * 4 + nd) * 512 +
                             (size_t)(qk * 16 + nl) * 8 + e;
                Qb[V16OFF + idx] = (__bf16)val;
            }
        }
    }
}

// ---- pass 1: Z_j = sum_i exp(s_ij - 16); 32 j/wave, Q staged in LDS ----
// grid (32 jb, 8 iy, 8 bh); block = 128 j; 8 chunks of 64 i, double-buffered.
__global__ __launch_bounds__(256) void k_colstats(float* __restrict__ ws) {
    __shared__ __bf16 qbuf[2][4096];
    int t = threadIdx.x, lane = t & 63, w = t >> 6;
    int jb = blockIdx.x, iy = blockIdx.y, bh = blockIdx.z;
    int jt0 = jb * 8 + w * 2;
    const __bf16* Qp = (const __bf16*)(ws + OFF_Q16);
    const __bf16* Kp = Qp + K16OFF;
    const __bf16* kb = Kp + (((size_t)bh * 256 + jt0) * 2) * 512 + lane * 8;
    bf16x8 bk00 = *(const bf16x8*)(kb);
    bf16x8 bk01 = *(const bf16x8*)(kb + 512);
    bf16x8 bk10 = *(const bf16x8*)(kb + 1024);
    bf16x8 bk11 = *(const bf16x8*)(kb + 1536);
    const __bf16* q0 = Qp + (((size_t)bh * 256 + iy * 32) * 2) * 512 +
                       w * 1024 + lane * 8;
    gload16(q0, qbuf[0] + w * 1024);
    gload16(q0 + 512, qbuf[0] + w * 1024 + 512);
    __syncthreads();
    float z0 = 0.f, z1 = 0.f;
    for (int ic = 0; ic < 8; ic++) {
        const __bf16* cur = qbuf[ic & 1];
        if (ic < 7) {
            const __bf16* qn = Qp + (((size_t)bh * 256 + iy * 32 + (ic + 1) * 4) * 2) * 512 +
                               w * 1024 + lane * 8;
            gload16(qn, qbuf[(ic + 1) & 1] + w * 1024);
            gload16(qn + 512, qbuf[(ic + 1) & 1] + w * 1024 + 512);
        }
#pragma unroll
        for (int it = 0; it < 4; it++) {
            bf16x8 a0 = *(const bf16x8*)(cur + it * 1024 + lane * 8);
            bf16x8 a1 = *(const bf16x8*)(cur + it * 1024 + 512 + lane * 8);
            f32x4 c0 = {0.f, 0.f, 0.f, 0.f};
            c0 = mf(a0, bk00, c0);
            c0 = mf(a1, bk01, c0);
            f32x4 c1 = {0.f, 0.f, 0.f, 0.f};
            c1 = mf(a0, bk10, c1);
            c1 = mf(a1, bk11, c1);
#pragma unroll
            for (int r = 0; r < 4; r++) {
                z0 += __expf(fmaf(c0[r], SCALE, -16.0f));
                z1 += __expf(fmaf(c1[r], SCALE, -16.0f));
            }
        }
        __syncthreads();
    }
    z0 += __shfl_xor(z0, 16, 64);
    z0 += __shfl_xor(z0, 32, 64);
    z1 += __shfl_xor(z1, 16, 64);
    z1 += __shfl_xor(z1, 32, 64);
    if (lane < 16) {
        size_t o = OFF_PZ + (size_t)iy * 32768 + (size_t)bh * SEQ + jt0 * 16 + lane;
        ws[o] = z0;
        ws[o + 16] = z1;
    }
}

// ---- pass 1b: a_j = -16 - ln(sum of 8 partials) ----
__global__ void k_afin(float* __restrict__ ws) {
    int idx = blockIdx.x * 256 + threadIdx.x;
    const float* pz = ws + OFF_PZ;
    float Z = 0.f;
#pragma unroll
    for (int iy = 0; iy < 8; iy++) Z += pz[(size_t)iy * 32768 + idx];
    ws[OFF_A + idx] = -16.0f - __logf(Z);
}

// ---- pass 2: 32 i/wave, K/V double-buffered in LDS, atomic fp32 epilogue ----
// grid (32 ib, 8 jy, 8 bh); block = 128 i; 16 chunks of 32 j.
__global__ __launch_bounds__(256) void k_attnpv(float* __restrict__ ws) {
    __shared__ __bf16 ldsK[2][2048], ldsV[2][2048], ptile[4 * 1280];
    int t = threadIdx.x, lane = t & 63, w = t >> 6;
    int jy = blockIdx.y, bh = blockIdx.z;
    int it0 = blockIdx.x * 8 + w * 2;
    int mrow = lane & 15, quad = lane >> 4;
    const __bf16* Qp = (const __bf16*)(ws + OFF_Q16);
    const __bf16* Kp = Qp + K16OFF;
    const __bf16* Vp = Qp + V16OFF;
    const float* Ac = ws + OFF_A + (size_t)bh * SEQ;
    __bf16* pt = ptile + w * 1280;

    const __bf16* qb = Qp + (((size_t)bh * 256 + it0) * 2) * 512 + lane * 8;
    bf16x8 aq00 = *(const bf16x8*)(qb);
    bf16x8 aq01 = *(const bf16x8*)(qb + 512);
    bf16x8 aq10 = *(const bf16x8*)(qb + 1024);
    bf16x8 aq11 = *(const bf16x8*)(qb + 1536);

    f32x4 oacc[2][4];
#pragma unroll
    for (int tt = 0; tt < 2; tt++)
#pragma unroll
        for (int nd = 0; nd < 4; nd++) oacc[tt][nd] = {0.f, 0.f, 0.f, 0.f};

    int jbase = jy * 512;
    {
        const __bf16* kg = Kp + (((size_t)bh * 256 + (jbase >> 4)) * 2) * 512 +
                           w * 512 + lane * 8;
        gload16(kg, ldsK[0] + w * 512);
        const __bf16* vg = Vp + (((size_t)bh * 128 + (jbase >> 5)) * 4) * 512 +
                           w * 512 + lane * 8;
        gload16(vg, ldsV[0] + w * 512);
    }
    __syncthreads();

    for (int jt = 0; jt < 16; jt++) {
        int j0 = jbase + jt * 32;
        const __bf16* curK = ldsK[jt & 1];
        const __bf16* curV = ldsV[jt & 1];
        if (jt < 15) {
            int jn = j0 + 32;
            const __bf16* kg = Kp + (((size_t)bh * 256 + (jn >> 4)) * 2) * 512 +
                               w * 512 + lane * 8;
            gload16(kg, ldsK[(jt + 1) & 1] + w * 512);
            const __bf16* vg = Vp + (((size_t)bh * 128 + (jn >> 5)) * 4) * 512 +
                               w * 512 + lane * 8;
            gload16(vg, ldsV[(jt + 1) & 1] + w * 512);
        }
        float ca0 = Ac[j0 + mrow], ca1 = Ac[j0 + 16 + mrow];
        bf16x8 ck0 = *(const bf16x8*)(curK + lane * 8);
        bf16x8 ck1 = *(const bf16x8*)(curK + 512 + lane * 8);
        bf16x8 ck2 = *(const bf16x8*)(curK + 1024 + lane * 8);
        bf16x8 ck3 = *(const bf16x8*)(curK + 1536 + lane * 8);
#pragma unroll
        for (int tt = 0; tt < 2; tt++) {
            bf16x8 a0 = tt ? aq10 : aq00;
            bf16x8 a1 = tt ? aq11 : aq01;
            f32x4 c0 = {0.f, 0.f, 0.f, 0.f};
            c0 = mf(a0, ck0, c0);
            c0 = mf(a1, ck1, c0);
            f32x4 c1 = {0.f, 0.f, 0.f, 0.f};
            c1 = mf(a0, ck2, c1);
            c1 = mf(a1, ck3, c1);
#pragma unroll
            for (int r = 0; r < 4; r++) {
                float p0 = __expf(fmaf(c0[r], SCALE, ca0));
                pt[(tt * 16 + quad * 4 + r) * 40 + mrow] = (__bf16)p0;
                float p1 = __expf(fmaf(c1[r], SCALE, ca1));
                pt[(tt * 16 + quad * 4 + r) * 40 + 16 + mrow] = (__bf16)p1;
            }
        }
        bf16x8 ap0 = *(const bf16x8*)(pt + mrow * 40 + quad * 8);
        bf16x8 ap1 = *(const bf16x8*)(pt + (16 + mrow) * 40 + quad * 8);
#pragma unroll
        for (int nd = 0; nd < 4; nd++) {
            bf16x8 bv = *(const bf16x8*)(curV + nd * 512 + lane * 8);
            oacc[0][nd] = mf(ap0, bv, oacc[0][nd]);
            oacc[1][nd] = mf(ap1, bv, oacc[1][nd]);
        }
        __syncthreads();
    }

    int b = bh >> 2, h = bh & 3;
    float* AO = ws + OFF_AO;
#pragma unroll
    for (int tt = 0; tt < 2; tt++) {
#pragma unroll
        for (int nd = 0; nd < 4; nd++) {
#pragma unroll
            for (int r = 0; r < 4; r++) {
                int i = (it0 + tt) * 16 + quad * 4 + r;
                int d = nd * 16 + mrow;
                atomicAdd(&AO[((size_t)(b * SEQ + i)) * 256 + h * 64 + d],
                          oacc[tt][nd][r]);
            }
        }
    }
}

// ---- output projection: fp32 AO -> bf16 frags inline, MFMA, fp32 out ----
__global__ __launch_bounds__(256) void k_outproj_mfma(const float* __restrict__ bo,
                                                      float* __restrict__ ws,
                                                      float* __restrict__ out) {
    int t = threadIdx.x, lane = t & 63, w = t >> 6;
    int row0 = blockIdx.x * 64 + w * 16;
    int mrow = lane & 15, quad = lane >> 4;
    const float* AO = ws + OFF_AO;
    const __bf16* W16 = (const __bf16*)(ws + OFF_W16) + (size_t)3 * 65536;
    f32x4 acc[16];
#pragma unroll
    for (int n = 0; n < 16; n++) acc[n] = {0.f, 0.f, 0.f, 0.f};
    const float* ap = AO + (size_t)(row0 + mrow) * 256 + quad * 8;
    const __bf16* bp = W16 + (size_t)mrow * 256 + quad * 8;
    for (int kc = 0; kc < 256; kc += 32) {
        float4 u = *(const float4*)(ap + kc);
        float4 v = *(const float4*)(ap + kc + 4);
        bf16x8 a = {(__bf16)u.x, (__bf16)u.y, (__bf16)u.z, (__bf16)u.w,
                    (__bf16)v.x, (__bf16)v.y, (__bf16)v.z, (__bf16)v.w};
#pragma unroll
        for (int nt = 0; nt < 16; nt++) {
            bf16x8 b = *(const bf16x8*)(bp + (size_t)nt * 16 * 256 + kc);
            acc[nt] = mf(a, b, acc[nt]);
        }
    }
#pragma unroll
    for (int nt = 0; nt < 16; nt++) {
        int n = nt * 16 + mrow;
        float bb = bo[n];
#pragma unroll
        for (int r = 0; r < 4; r++) {
            int sg = row0 + quad * 4 + r;
            out[(size_t)sg * 256 + n] = acc[nt][r] + bb;
        }
    }
}

extern "C" void kernel_launch(void* const* d_in, const int* in_sizes, int n_in,
                              void* d_out, int out_size, void* d_ws, size_t ws_size,
                              hipStream_t stream) {
    const float* x  = (const float*)d_in[0];
    const float* wq = (const float*)d_in[1];
    const float* bq = (const float*)d_in[2];
    const float* wk = (const float*)d_in[3];
    const float* bk = (const float*)d_in[4];
    const float* wv = (const float*)d_in[5];
    const float* bv = (const float*)d_in[6];
    const float* wo = (const float*)d_in[7];
    const float* bo = (const float*)d_in[8];
    float* ws = (float*)d_ws;
    float* out = (float*)d_out;

    k_prep<<<8448, 256, 0, stream>>>(x, wq, wk, wv, wo, ws);
    k_qkv_mfma<<<dim3(128, 3), 256, 0, stream>>>(bq, bk, bv, ws);
    k_colstats<<<dim3(32, 8, 8), 256, 0, stream>>>(ws);
    k_afin<<<128, 256, 0, stream>>>(ws);
    k_attnpv<<<dim3(32, 8, 8), 256, 0, stream>>>(ws);
    k_outproj_mfma<<<128, 256, 0, stream>>>(bo, ws, out);
}

// Round 15
// 249.946 us; speedup vs baseline: 1.2623x; 1.0316x over previous
//
#include <hip/hip_runtime.h>

#define SEQ   4096
#define HH    4
// exp(s) = 2^(c*SK2 + ...): SK2 = 0.125*log2(e), MB2 = -16*log2(e)
#define SK2 0.18033688011112042f
#define MB2 -23.083120654223414f

typedef __bf16 bf16x8 __attribute__((ext_vector_type(8)));
typedef __bf16 bf16x4 __attribute__((ext_vector_type(4)));
typedef short  s16x4  __attribute__((ext_vector_type(4)));
typedef float  f32x4  __attribute__((ext_vector_type(4)));

// ---- ws layout (float offsets) ----
// Facts: inputs fp32, output fp32 (R6), ws >= 70.5 MB (R2==R3).
// Q,K frag-packed [bh][tile16][frag2][lane64][e8].
// V packed as B-frags of 16x16x16 (n=d, k=j): [bh][jc16][nd4][lane64][e4]
//   (numerically verified in R13).
constexpr size_t OFF_W16  = 0;         // 4x65536 bf16 weights row-major
constexpr size_t OFF_A    = 131072;    // [bh*S+j] a'_j = MB2 - log2(Z'_j)
constexpr size_t OFF_PZ   = 163840;    // [8][32768] partial sums
constexpr size_t OFF_AO   = 425984;    // [8192][256] fp32 attn out (atomic)
constexpr size_t OFF_X16  = 9732096;   // 6291456 bf16 (x cast)
constexpr size_t OFF_Q16  = 12877824;  // packed Q,K,V bf16 regions
constexpr size_t K16OFF   = 2097152;
constexpr size_t V16OFF   = 4194304;

__device__ __forceinline__ f32x4 mf(bf16x8 a, bf16x8 b, f32x4 c) {
    return __builtin_amdgcn_mfma_f32_16x16x32_bf16(a, b, c, 0, 0, 0);
}

// K=16 bf16 MFMA: A = P (m=i, k=j local), B = V (n=d, k=j) -> D = O (R12 C-layout)
__device__ __forceinline__ f32x4 mf16(bf16x4 a, bf16x4 b, f32x4 c) {
#if __has_builtin(__builtin_amdgcn_mfma_f32_16x16x16bf16_1k)
    s16x4 as = __builtin_bit_cast(s16x4, a);
    s16x4 bs = __builtin_bit_cast(s16x4, b);
    return __builtin_amdgcn_mfma_f32_16x16x16bf16_1k(as, bs, c, 0, 0, 0);
#else
    f32x4 d = c;
    asm("v_mfma_f32_16x16x16_bf16 %0, %1, %2, %0" : "+v"(d) : "v"(a), "v"(b));
    return d;
#endif
}

__device__ __forceinline__ float fexp2(float x) {
#if __has_builtin(__builtin_amdgcn_exp2f)
    return __builtin_amdgcn_exp2f(x);
#else
    return exp2f(x);
#endif
}

// async global->LDS, 16B/lane
__device__ __forceinline__ void gload16(const __bf16* g, __bf16* l) {
    __builtin_amdgcn_global_load_lds(
        (const __attribute__((address_space(1))) unsigned int*)g,
        (__attribute__((address_space(3))) unsigned int*)l, 16, 0, 0);
}

// ---- prep: cast x, cast weights, zero AO ----
__global__ void k_prep(const float* __restrict__ x,
                       const float* __restrict__ wq, const float* __restrict__ wk,
                       const float* __restrict__ wv, const float* __restrict__ wo,
                       float* __restrict__ ws) {
    int bx = blockIdx.x, t = threadIdx.x;
    if (bx < 6144) {
        size_t i4 = ((size_t)bx * 256 + t) * 4;
        float4 v = *(const float4*)(x + i4);
        bf16x4 o = {(__bf16)v.x, (__bf16)v.y, (__bf16)v.z, (__bf16)v.w};
        *(bf16x4*)((__bf16*)(ws + OFF_X16) + i4) = o;
    } else if (bx < 6400) {
        int q = bx - 6144;
        int y = q >> 6;
        const float* src = (y == 0) ? wq : (y == 1) ? wk : (y == 2) ? wv : wo;
        size_t i4 = ((size_t)(q & 63) * 256 + t) * 4;
        float4 v = *(const float4*)(src + i4);
        bf16x4 o = {(__bf16)v.x, (__bf16)v.y, (__bf16)v.z, (__bf16)v.w};
        *(bf16x4*)((__bf16*)(ws + OFF_W16) + (size_t)y * 65536 + i4) = o;
    } else {
        size_t i4 = ((size_t)(bx - 6400) * 256 + t) * 4;
        *(float4*)(ws + OFF_AO + i4) = make_float4(0.f, 0.f, 0.f, 0.f);
    }
}

// ---- QKV projection via MFMA; V epilogue -> 16x16x16 B-frag layout ----
__global__ __launch_bounds__(256) void k_qkv_mfma(const float* __restrict__ bq,
                                                  const float* __restrict__ bk,
                                                  const float* __restrict__ bv,
                                                  float* __restrict__ ws) {
    int t = threadIdx.x, lane = t & 63, w = t >> 6;
    int yw = blockIdx.y;
    int row0 = blockIdx.x * 64 + w * 16;
    int mrow = lane & 15, quad = lane >> 4;
    const __bf16* X16 = (const __bf16*)(ws + OFF_X16);
    const __bf16* W16 = (const __bf16*)(ws + OFF_W16) + (size_t)yw * 65536;
    const float* bias = (yw == 0) ? bq : (yw == 1) ? bk : bv;
    __bf16* Qb = (__bf16*)(ws + OFF_Q16);
    f32x4 acc[16];
#pragma unroll
    for (int n = 0; n < 16; n++) acc[n] = {0.f, 0.f, 0.f, 0.f};
    const __bf16* ap = X16 + (size_t)(row0 + mrow) * 768 + yw * 256 + quad * 8;
    const __bf16* bp = W16 + (size_t)mrow * 256 + quad * 8;
    for (int kc = 0; kc < 256; kc += 32) {
        bf16x8 a = *(const bf16x8*)(ap + kc);
#pragma unroll
        for (int nt = 0; nt < 16; nt++) {
            bf16x8 b = *(const bf16x8*)(bp + (size_t)nt * 16 * 256 + kc);
            acc[nt] = mf(a, b, acc[nt]);
        }
    }
#pragma unroll
    for (int nt = 0; nt < 16; nt++) {
        int n = nt * 16 + mrow;
        float bb = bias[n];
        int h = n >> 6, d = n & 63;
#pragma unroll
        for (int r = 0; r < 4; r++) {
            int sg = row0 + quad * 4 + r;
            int b_ = sg >> 12, s = sg & 4095;
            int bh = b_ * HH + h;
            float val = acc[nt][r] + bb;
            if (yw <= 1) {
                int tile = s >> 4, m = s & 15, frag = d >> 5, q2 = (d >> 3) & 3, e = d & 7;
                size_t idx = (((size_t)bh * 256 + tile) * 2 + frag) * 512 +
                             (size_t)(q2 * 16 + m) * 8 + e;
                ((yw == 0) ? Qb : Qb + K16OFF)[idx] = (__bf16)val;
            } else {
                // V B-frag (16x16x16): [bh][jc=s>>4][nd=d>>4][(jq*16+dl)*4+je]
                int jc = s >> 4, jq = (s >> 2) & 3, je = s & 3;
                int nd = d >> 4, dl = d & 15;
                size_t idx = (((size_t)bh * 256 + jc) * 4 + nd) * 256 +
                             (size_t)(jq * 16 + dl) * 4 + je;
                Qb[V16OFF + idx] = (__bf16)val;
            }
        }
    }
}

// ---- pass 1: Z'_j = sum_i 2^(c*SK2 + MB2); 32 j/wave, Q staged in LDS ----
__global__ __launch_bounds__(256) void k_colstats(float* __restrict__ ws) {
    __shared__ __bf16 qbuf[2][4096];
    int t = threadIdx.x, lane = t & 63, w = t >> 6;
    int jb = blockIdx.x, iy = blockIdx.y, bh = blockIdx.z;
    int jt0 = jb * 8 + w * 2;
    const __bf16* Qp = (const __bf16*)(ws + OFF_Q16);
    const __bf16* Kp = Qp + K16OFF;
    const __bf16* kb = Kp + (((size_t)bh * 256 + jt0) * 2) * 512 + lane * 8;
    bf16x8 bk00 = *(const bf16x8*)(kb);
    bf16x8 bk01 = *(const bf16x8*)(kb + 512);
    bf16x8 bk10 = *(const bf16x8*)(kb + 1024);
    bf16x8 bk11 = *(const bf16x8*)(kb + 1536);
    const __bf16* q0 = Qp + (((size_t)bh * 256 + iy * 32) * 2) * 512 +
                       w * 1024 + lane * 8;
    gload16(q0, qbuf[0] + w * 1024);
    gload16(q0 + 512, qbuf[0] + w * 1024 + 512);
    __syncthreads();
    float z0 = 0.f, z1 = 0.f;
    for (int ic = 0; ic < 8; ic++) {
        const __bf16* cur = qbuf[ic & 1];
        if (ic < 7) {
            const __bf16* qn = Qp + (((size_t)bh * 256 + iy * 32 + (ic + 1) * 4) * 2) * 512 +
                               w * 1024 + lane * 8;
            gload16(qn, qbuf[(ic + 1) & 1] + w * 1024);
            gload16(qn + 512, qbuf[(ic + 1) & 1] + w * 1024 + 512);
        }
#pragma unroll
        for (int it = 0; it < 4; it++) {
            bf16x8 a0 = *(const bf16x8*)(cur + it * 1024 + lane * 8);
            bf16x8 a1 = *(const bf16x8*)(cur + it * 1024 + 512 + lane * 8);
            f32x4 c0 = {0.f, 0.f, 0.f, 0.f};
            c0 = mf(a0, bk00, c0);
            c0 = mf(a1, bk01, c0);
            f32x4 c1 = {0.f, 0.f, 0.f, 0.f};
            c1 = mf(a0, bk10, c1);
            c1 = mf(a1, bk11, c1);
#pragma unroll
            for (int r = 0; r < 4; r++) {
                z0 += fexp2(fmaf(c0[r], SK2, MB2));
                z1 += fexp2(fmaf(c1[r], SK2, MB2));
            }
        }
        __syncthreads();
    }
    z0 += __shfl_xor(z0, 16, 64);
    z0 += __shfl_xor(z0, 32, 64);
    z1 += __shfl_xor(z1, 16, 64);
    z1 += __shfl_xor(z1, 32, 64);
    if (lane < 16) {
        size_t o = OFF_PZ + (size_t)iy * 32768 + (size_t)bh * SEQ + jt0 * 16 + lane;
        ws[o] = z0;
        ws[o + 16] = z1;
    }
}

// ---- pass 1b: a'_j = MB2 - log2(sum of 8 partials) ----
__global__ void k_afin(float* __restrict__ ws) {
    int idx = blockIdx.x * 256 + threadIdx.x;
    const float* pz = ws + OFF_PZ;
    float Z = 0.f;
#pragma unroll
    for (int iy = 0; iy < 8; iy++) Z += pz[(size_t)iy * 32768 + idx];
    ws[OFF_A + idx] = MB2 - __log2f(Z);
}

// ---- pass 2: S^T scores; P flows register-direct into K=16 PV MFMA ----
// grid (32 ib, 8 jy, 8 bh); wave owns 32 i; 16 chunks of 32 j; no P LDS.
// S^T = mf(K,Q): lane holds (i=lane&15, j=quad*4+r) == A-frag of 16x16x16.
__global__ __launch_bounds__(256) void k_attnpv(float* __restrict__ ws) {
    __shared__ __bf16 ldsK[2][2048], ldsV[2][2048];
    int t = threadIdx.x, lane = t & 63, w = t >> 6;
    int jy = blockIdx.y, bh = blockIdx.z;
    int it0 = blockIdx.x * 8 + w * 2;
    int mrow = lane & 15, quad = lane >> 4;
    const __bf16* Qp = (const __bf16*)(ws + OFF_Q16);
    const __bf16* Kp = Qp + K16OFF;
    const __bf16* Vp = Qp + V16OFF;
    const float* Ac = ws + OFF_A + (size_t)bh * SEQ;

    const __bf16* qb = Qp + (((size_t)bh * 256 + it0) * 2) * 512 + lane * 8;
    bf16x8 qf[2][2];
    qf[0][0] = *(const bf16x8*)(qb);
    qf[0][1] = *(const bf16x8*)(qb + 512);
    qf[1][0] = *(const bf16x8*)(qb + 1024);
    qf[1][1] = *(const bf16x8*)(qb + 1536);

    f32x4 oacc[2][4];
#pragma unroll
    for (int tt = 0; tt < 2; tt++)
#pragma unroll
        for (int nd = 0; nd < 4; nd++) oacc[tt][nd] = {0.f, 0.f, 0.f, 0.f};

    int jbase = jy * 512;
    {
        const __bf16* kg = Kp + (((size_t)bh * 256 + (jbase >> 4)) * 2) * 512 +
                           w * 512 + lane * 8;
        gload16(kg, ldsK[0] + w * 512);
        const __bf16* vg = Vp + ((size_t)bh * 256 + (jbase >> 4)) * 1024 +
                           w * 512 + lane * 8;
        gload16(vg, ldsV[0] + w * 512);
    }
    __syncthreads();

    for (int jt = 0; jt < 16; jt++) {
        int j0 = jbase + jt * 32;
        const __bf16* curK = ldsK[jt & 1];
        const __bf16* curV = ldsV[jt & 1];
        if (jt < 15) {
            int jn = j0 + 32;
            const __bf16* kg = Kp + (((size_t)bh * 256 + (jn >> 4)) * 2) * 512 +
                               w * 512 + lane * 8;
            gload16(kg, ldsK[(jt + 1) & 1] + w * 512);
            const __bf16* vg = Vp + ((size_t)bh * 256 + (jn >> 4)) * 1024 +
                               w * 512 + lane * 8;
            gload16(vg, ldsV[(jt + 1) & 1] + w * 512);
        }
#pragma unroll
        for (int jj = 0; jj < 2; jj++) {
            // K A-frags (m=j): identical packing to B-usage, symmetric layout
            bf16x8 kf0 = *(const bf16x8*)(curK + (jj * 2) * 512 + lane * 8);
            bf16x8 kf1 = *(const bf16x8*)(curK + (jj * 2 + 1) * 512 + lane * 8);
            // a' for j = j0 + jj*16 + quad*4 + r
            float4 af = *(const float4*)(Ac + j0 + jj * 16 + quad * 4);
            // V B-frags (n=d, k=j local)
            bf16x4 vf[4];
#pragma unroll
            for (int nd = 0; nd < 4; nd++)
                vf[nd] = *(const bf16x4*)(curV + (jj * 4 + nd) * 256 + lane * 4);
#pragma unroll
            for (int tt = 0; tt < 2; tt++) {
                f32x4 c = {0.f, 0.f, 0.f, 0.f};
                c = mf(kf0, qf[tt][0], c);   // S^T: m=j, n=i
                c = mf(kf1, qf[tt][1], c);
                bf16x4 pf;
                pf[0] = (__bf16)fexp2(fmaf(c[0], SK2, af.x));
                pf[1] = (__bf16)fexp2(fmaf(c[1], SK2, af.y));
                pf[2] = (__bf16)fexp2(fmaf(c[2], SK2, af.z));
                pf[3] = (__bf16)fexp2(fmaf(c[3], SK2, af.w));
#pragma unroll
                for (int nd = 0; nd < 4; nd++)
                    oacc[tt][nd] = mf16(pf, vf[nd], oacc[tt][nd]);
            }
        }
        __syncthreads();
    }

    int b = bh >> 2, h = bh & 3;
    float* AO = ws + OFF_AO;
#pragma unroll
    for (int tt = 0; tt < 2; tt++) {
#pragma unroll
        for (int nd = 0; nd < 4; nd++) {
#pragma unroll
            for (int r = 0; r < 4; r++) {
                int i = (it0 + tt) * 16 + quad * 4 + r;
                int d = nd * 16 + mrow;
                atomicAdd(&AO[((size_t)(b * SEQ + i)) * 256 + h * 64 + d],
                          oacc[tt][nd][r]);
            }
        }
    }
}

// ---- output projection: fp32 AO -> bf16 frags inline, MFMA, fp32 out ----
__global__ __launch_bounds__(256) void k_outproj_mfma(const float* __restrict__ bo,
                                                      float* __restrict__ ws,
                                                      float* __restrict__ out) {
    int t = threadIdx.x, lane = t & 63, w = t >> 6;
    int row0 = blockIdx.x * 64 + w * 16;
    int mrow = lane & 15, quad = lane >> 4;
    const float* AO = ws + OFF_AO;
    const __bf16* W16 = (const __bf16*)(ws + OFF_W16) + (size_t)3 * 65536;
    f32x4 acc[16];
#pragma unroll
    for (int n = 0; n < 16; n++) acc[n] = {0.f, 0.f, 0.f, 0.f};
    const float* ap = AO + (size_t)(row0 + mrow) * 256 + quad * 8;
    const __bf16* bp = W16 + (size_t)mrow * 256 + quad * 8;
    for (int kc = 0; kc < 256; kc += 32) {
        float4 u = *(const float4*)(ap + kc);
        float4 v = *(const float4*)(ap + kc + 4);
        bf16x8 a = {(__bf16)u.x, (__bf16)u.y, (__bf16)u.z, (__bf16)u.w,
                    (__bf16)v.x, (__bf16)v.y, (__bf16)v.z, (__bf16)v.w};
#pragma unroll
        for (int nt = 0; nt < 16; nt++) {
            bf16x8 b = *(const bf16x8*)(bp + (size_t)nt * 16 * 256 + kc);
            acc[nt] = mf(a, b, acc[nt]);
        }
    }
#pragma unroll
    for (int nt = 0; nt < 16; nt++) {
        int n = nt * 16 + mrow;
        float bb = bo[n];
#pragma unroll
        for (int r = 0; r < 4; r++) {
            int sg = row0 + quad * 4 + r;
            out[(size_t)sg * 256 + n] = acc[nt][r] + bb;
        }
    }
}

extern "C" void kernel_launch(void* const* d_in, const int* in_sizes, int n_in,
                              void* d_out, int out_size, void* d_ws, size_t ws_size,
                              hipStream_t stream) {
    const float* x  = (const float*)d_in[0];
    const float* wq = (const float*)d_in[1];
    const float* bq = (const float*)d_in[2];
    const float* wk = (const float*)d_in[3];
    const float* bk = (const float*)d_in[4];
    const float* wv = (const float*)d_in[5];
    const float* bv = (const float*)d_in[6];
    const float* wo = (const float*)d_in[7];
    const float* bo = (const float*)d_in[8];
    float* ws = (float*)d_ws;
    float* out = (float*)d_out;

    k_prep<<<8448, 256, 0, stream>>>(x, wq, wk, wv, wo, ws);
    k_qkv_mfma<<<dim3(128, 3), 256, 0, stream>>>(bq, bk, bv, ws);
    k_colstats<<<dim3(32, 8, 8), 256, 0, stream>>>(ws);
    k_afin<<<128, 256, 0, stream>>>(ws);
    k_attnpv<<<dim3(32, 8, 8), 256, 0, stream>>>(ws);
    k_outproj_mfma<<<128, 256, 0, stream>>>(bo, ws, out);
}